// Round 3
// baseline (217.528 us; speedup 1.0000x reference)
//
#include <hip/hip_runtime.h>

#define T_LEN 200
#define F_IN  32
#define TC    8                 // timesteps per chunk; 200 = 25 * 8
#define NCH   (T_LEN / TC)
#define NB    16                // batches per block: 2 streams x 8
#define PSTR  264               // P stride per batch (dwords): 8t*32 + 8 pad -> 2-way banks (free)
#define ZSTR  204               // z stride per batch (dwords), 16B-aligned rows

#define QP(a,b,c,d) ((a)|((b)<<2)|((c)<<4)|((d)<<6))
#define DPP_HM 0x141            // row_half_mirror: lane^7 within each 8-group

typedef short  bf16x8  __attribute__((ext_vector_type(8)));
typedef float  floatx4 __attribute__((ext_vector_type(4)));

template <int CTRL>
__device__ __forceinline__ float dppf(float v) {
    return __int_as_float(__builtin_amdgcn_update_dpp(
        0, __float_as_int(v), CTRL, 0xF, 0xF, true));
}
// truncation bf16 split: x ~= hi + lo, |err| ~ 2^-16 rel
__device__ __forceinline__ void bfsplit(float x, short& hi, short& lo) {
    unsigned u = __float_as_uint(x);
    unsigned short h = (unsigned short)(u >> 16);
    float fh = __uint_as_float(((unsigned)h) << 16);
    float r  = x - fh;
    hi = (short)h;
    lo = (short)(__float_as_uint(r) >> 16);
}

__launch_bounds__(128, 1)
__global__ void mono_lstm_kernel(const float* __restrict__ x,
                                 const float* __restrict__ z0,
                                 const float* __restrict__ W_ih,
                                 const float* __restrict__ W_hh,
                                 const float* __restrict__ b_ih,
                                 const float* __restrict__ b_hh,
                                 const float* __restrict__ W1,
                                 const float* __restrict__ b1,
                                 const float* __restrict__ W2,
                                 const float* __restrict__ b2,
                                 float* __restrict__ out) {
    __shared__ float pls[2 * NB * PSTR];   // P double buffer (33.8 KB)
    __shared__ float zls[NB * ZSTR];       // z output buffer (13.1 KB)

    const int tid  = threadIdx.x;         // 0..127: wave0 = consumer, wave1 = producer
    const int lane = tid & 63;
    const int wv   = tid >> 6;
    const int bl   = lane >> 3;           // local batch 0..7 (per stream)
    const int j    = lane & 7;            // hidden unit owned by this lane
    const int bg   = blockIdx.x * NB;

    const float L2E = 1.4426950408889634f;
    const float NSC = -L2E;               // i,f,o scale (negated for exp2(-u))
    const float NSG = -2.0f * L2E;        // g scale (tanh u = 2*sig(2u)-1)

    // ================= producer (wave 1) state =================
    const int n  = lane & 15;             // MFMA N index
    const int kq = lane >> 4;
    bf16x8 Bh0, Bl0, Bh1, Bl1;
    float bias0 = 0.f, bias1 = 0.f;

    // A-fragment addressing: m = lane&15 -> (batch m>>1, t-parity m&1); k = kq*8..
    const int   am  = lane & 15;
    const float* xa0 = x + ((size_t)(bg + (am >> 1)) * T_LEN + (am & 1)) * F_IN + kq * 8;
    const float* xa1 = xa0 + (size_t)8 * T_LEN * F_IN;   // stream-1 batches (+8)

    float4 rgv[2][8];
    auto load_x = [&](int ch) {   // x for chunk ch -> registers (both streams)
#pragma unroll
        for (int sub = 0; sub < 2; ++sub) {
            const float* xa = sub ? xa1 : xa0;
#pragma unroll
            for (int s = 0; s < 4; ++s) {
                const float* p = xa + (size_t)(ch * TC + 2 * s) * F_IN;
                rgv[sub][2 * s]     = *(const float4*)p;
                rgv[sub][2 * s + 1] = *(const float4*)(p + 4);
            }
        }
    };
    auto mfma_phase = [&](int buf) {  // P(chunk) from rgv -> pls[buf], both streams
#pragma unroll
        for (int sub = 0; sub < 2; ++sub) {
#pragma unroll
            for (int s = 0; s < 4; ++s) {
                const float xv[8] = {rgv[sub][2*s].x, rgv[sub][2*s].y, rgv[sub][2*s].z, rgv[sub][2*s].w,
                                     rgv[sub][2*s+1].x, rgv[sub][2*s+1].y, rgv[sub][2*s+1].z, rgv[sub][2*s+1].w};
                bf16x8 Ah, Al;
#pragma unroll
                for (int i = 0; i < 8; ++i) {
                    short h, l;
                    bfsplit(xv[i], h, l);
                    Ah[i] = h; Al[i] = l;
                }
                floatx4 a0 = {bias0, bias0, bias0, bias0};
                floatx4 a1 = {bias1, bias1, bias1, bias1};
                a0 = __builtin_amdgcn_mfma_f32_16x16x32_bf16(Ah, Bh0, a0, 0, 0, 0);
                a0 = __builtin_amdgcn_mfma_f32_16x16x32_bf16(Al, Bh0, a0, 0, 0, 0);
                a0 = __builtin_amdgcn_mfma_f32_16x16x32_bf16(Ah, Bl0, a0, 0, 0, 0);
                a1 = __builtin_amdgcn_mfma_f32_16x16x32_bf16(Ah, Bh1, a1, 0, 0, 0);
                a1 = __builtin_amdgcn_mfma_f32_16x16x32_bf16(Al, Bh1, a1, 0, 0, 0);
                a1 = __builtin_amdgcn_mfma_f32_16x16x32_bf16(Ah, Bl1, a1, 0, 0, 0);
#pragma unroll
                for (int reg = 0; reg < 4; ++reg) {
                    const int mr = (lane >> 4) * 4 + reg;      // C/D row = A m-row
                    const int bb = sub * 8 + (mr >> 1), tt = 2 * s + (mr & 1);
                    pls[buf * NB * PSTR + bb * PSTR + tt * 32 + n]      = a0[reg];
                    pls[buf * NB * PSTR + bb * PSTR + tt * 32 + 16 + n] = a1[reg];
                }
            }
        }
    };

    // ================= consumer (wave 0) state =================
    float whi[8], whf[8], whg[8], who[8];
    float wzi = 0.f, wzf = 0.f, wzg = 0.f, wzo = 0.f;
    float w1h[5][8], b1v[5], w2v[5];
    float b2v = 0.f;
    float ha[2][8];                       // h_{j^k} per stream
    float cst[2] = {0.f, 0.f};
    float zst[2] = {0.f, 0.f};
    float zk[2]  = {0.f, 0.f};            // z kept at t == j (per chunk)
#pragma unroll
    for (int st = 0; st < 2; ++st)
#pragma unroll
        for (int k = 0; k < 8; ++k) ha[st][k] = 0.f;

    if (wv == 1) {
        // ---- MFMA B fragments: N-tile0 rows 0..15 (i,f), tile1 rows 16..31 (g,o)
        const int row0 = n, row1 = 16 + n;
        const float sc0 = NSC;                       // rows 0..15 all i/f
        const float sc1 = (n < 8) ? NSG : NSC;       // g rows then o rows
#pragma unroll
        for (int i = 0; i < 8; ++i) {
            const int k = kq * 8 + i;
            short h, l;
            bfsplit(W_ih[row0 * 33 + k] * sc0, h, l); Bh0[i] = h; Bl0[i] = l;
            bfsplit(W_ih[row1 * 33 + k] * sc1, h, l); Bh1[i] = h; Bl1[i] = l;
        }
        bias0 = (b_ih[row0] + b_hh[row0]) * sc0;
        bias1 = (b_ih[row1] + b_hh[row1]) * sc1;

        // ---- prologue: P(0) into buf0, x(1) into registers
        load_x(0);
        mfma_phase(0);
        load_x(1);
    } else {
        // ---- recurrence weights (per lane, xor-gather order) ----
        const int ri = j, rf = 8 + j, rg_ = 16 + j, ro = 24 + j;
#pragma unroll
        for (int k = 0; k < 8; ++k) {
            whi[k] = W_hh[ri * 8 + (j ^ k)] * NSC;
            whf[k] = W_hh[rf * 8 + (j ^ k)] * NSC;
            whg[k] = W_hh[rg_ * 8 + (j ^ k)] * NSG;
            who[k] = W_hh[ro * 8 + (j ^ k)] * NSC;
        }
        wzi = W_ih[ri * 33 + 32] * NSC;
        wzf = W_ih[rf * 33 + 32] * NSC;
        wzg = W_ih[rg_ * 33 + 32] * NSG;
        wzo = W_ih[ro * 33 + 32] * NSC;

        // ---- head weights: full head per lane (xor-permuted cols) ----
#pragma unroll
        for (int m = 0; m < 5; ++m) {
#pragma unroll
            for (int k = 0; k < 8; ++k) w1h[m][k] = W1[m * 8 + (j ^ k)];
            b1v[m] = b1[m];
            w2v[m] = W2[m];
        }
        b2v = b2[0];
        zst[0] = z0[bg + bl];
        zst[1] = z0[bg + 8 + bl];
    }

    __syncthreads();   // P(0) ready

    for (int ch = 0; ch < NCH; ++ch) {
        if (wv == 1) {
            // producer: P(ch+1) into the other buffer while consumer eats P(ch)
            if (ch + 1 < NCH) {
                mfma_phase((ch + 1) & 1);
                if (ch + 2 < NCH) load_x(ch + 2);
            }
        } else {
            const int base = (ch & 1) * NB * PSTR;
            // two half-chunk passes: limits live P registers to 2*4*4 = 32
#pragma unroll
            for (int half = 0; half < 2; ++half) {
                float pv[2][4][4];     // [stream][gate][t-in-half]
#pragma unroll
                for (int st = 0; st < 2; ++st) {
                    const int rbase = base + (st * 8 + bl) * PSTR;
#pragma unroll
                    for (int tt = 0; tt < 4; ++tt) {
                        const int a = rbase + (half * 4 + tt) * 32 + j;
                        pv[st][0][tt] = pls[a];
                        pv[st][1][tt] = pls[a + 8];
                        pv[st][2][tt] = pls[a + 16];
                        pv[st][3][tt] = pls[a + 24];
                    }
                }

#pragma unroll
                for (int tt = 0; tt < 4; ++tt) {
                    const int t = half * 4 + tt;
#pragma unroll
                    for (int st = 0; st < 2; ++st) {
                        // matvec (off z-path: starts from ha*), then +wz*z last
                        float mi = fmaf(whi[0], ha[st][0], fmaf(whi[1], ha[st][1],
                                   fmaf(whi[2], ha[st][2], fmaf(whi[3], ha[st][3], pv[st][0][tt]))));
                        float ni = fmaf(whi[4], ha[st][4], fmaf(whi[5], ha[st][5],
                                   fmaf(whi[6], ha[st][6], whi[7] * ha[st][7])));
                        float mf = fmaf(whf[0], ha[st][0], fmaf(whf[1], ha[st][1],
                                   fmaf(whf[2], ha[st][2], fmaf(whf[3], ha[st][3], pv[st][1][tt]))));
                        float nf = fmaf(whf[4], ha[st][4], fmaf(whf[5], ha[st][5],
                                   fmaf(whf[6], ha[st][6], whf[7] * ha[st][7])));
                        float mg = fmaf(whg[0], ha[st][0], fmaf(whg[1], ha[st][1],
                                   fmaf(whg[2], ha[st][2], fmaf(whg[3], ha[st][3], pv[st][2][tt]))));
                        float ng = fmaf(whg[4], ha[st][4], fmaf(whg[5], ha[st][5],
                                   fmaf(whg[6], ha[st][6], whg[7] * ha[st][7])));
                        float mo = fmaf(who[0], ha[st][0], fmaf(who[1], ha[st][1],
                                   fmaf(who[2], ha[st][2], fmaf(who[3], ha[st][3], pv[st][3][tt]))));
                        float no = fmaf(who[4], ha[st][4], fmaf(who[5], ha[st][5],
                                   fmaf(who[6], ha[st][6], who[7] * ha[st][7])));

                        const float ai = fmaf(wzi, zst[st], mi + ni);
                        const float af = fmaf(wzf, zst[st], mf + nf);
                        const float ag = fmaf(wzg, zst[st], mg + ng);
                        const float ao = fmaf(wzo, zst[st], mo + no);

                        // activations: acc pre-scaled by -log2e (or -2log2e for g)
                        const float si = __builtin_amdgcn_rcpf(1.0f + __builtin_amdgcn_exp2f(ai));
                        const float sf = __builtin_amdgcn_rcpf(1.0f + __builtin_amdgcn_exp2f(af));
                        const float sg = __builtin_amdgcn_rcpf(1.0f + __builtin_amdgcn_exp2f(ag));
                        const float so = __builtin_amdgcn_rcpf(1.0f + __builtin_amdgcn_exp2f(ao));
                        const float tg = fmaf(2.0f, sg, -1.0f);      // tanh(g)

                        cst[st] = fmaf(sf, cst[st], si * tg);
                        const float ec = __builtin_amdgcn_exp2f(cst[st] * (-2.0f * L2E));
                        const float tc = fmaf(2.0f, __builtin_amdgcn_rcpf(1.0f + ec), -1.0f);
                        const float hn = so * tc;                    // h_j

                        // gather h_{j^k}: pure DPP within the 8-lane group, depth 2
                        ha[st][0] = hn;
                        ha[st][1] = dppf<QP(1, 0, 3, 2)>(hn);
                        ha[st][2] = dppf<QP(2, 3, 0, 1)>(hn);
                        ha[st][3] = dppf<QP(3, 2, 1, 0)>(hn);
                        const float t7 = dppf<DPP_HM>(hn);
                        ha[st][7] = t7;
                        ha[st][4] = dppf<QP(3, 2, 1, 0)>(t7);
                        ha[st][5] = dppf<QP(2, 3, 0, 1)>(t7);
                        ha[st][6] = dppf<QP(1, 0, 3, 2)>(t7);

                        // head: fully per-lane (redundant x8, zero cross-lane)
                        float d0a = fmaf(w1h[0][0], ha[st][0], fmaf(w1h[0][1], ha[st][1], fmaf(w1h[0][2], ha[st][2], b1v[0])));
                        float d0b = fmaf(w1h[0][4], ha[st][4], fmaf(w1h[0][5], ha[st][5], fmaf(w1h[0][6], ha[st][6], w1h[0][7] * ha[st][7])));
                        float d1a = fmaf(w1h[1][0], ha[st][0], fmaf(w1h[1][1], ha[st][1], fmaf(w1h[1][2], ha[st][2], b1v[1])));
                        float d1b = fmaf(w1h[1][4], ha[st][4], fmaf(w1h[1][5], ha[st][5], fmaf(w1h[1][6], ha[st][6], w1h[1][7] * ha[st][7])));
                        float d2a = fmaf(w1h[2][0], ha[st][0], fmaf(w1h[2][1], ha[st][1], fmaf(w1h[2][2], ha[st][2], b1v[2])));
                        float d2b = fmaf(w1h[2][4], ha[st][4], fmaf(w1h[2][5], ha[st][5], fmaf(w1h[2][6], ha[st][6], w1h[2][7] * ha[st][7])));
                        float d3a = fmaf(w1h[3][0], ha[st][0], fmaf(w1h[3][1], ha[st][1], fmaf(w1h[3][2], ha[st][2], b1v[3])));
                        float d3b = fmaf(w1h[3][4], ha[st][4], fmaf(w1h[3][5], ha[st][5], fmaf(w1h[3][6], ha[st][6], w1h[3][7] * ha[st][7])));
                        float d4a = fmaf(w1h[4][0], ha[st][0], fmaf(w1h[4][1], ha[st][1], fmaf(w1h[4][2], ha[st][2], b1v[4])));
                        float d4b = fmaf(w1h[4][4], ha[st][4], fmaf(w1h[4][5], ha[st][5], fmaf(w1h[4][6], ha[st][6], w1h[4][7] * ha[st][7])));
                        const float d0 = fmaxf(fmaf(w1h[0][3], ha[st][3], d0a + d0b), 0.0f);
                        const float d1 = fmaxf(fmaf(w1h[1][3], ha[st][3], d1a + d1b), 0.0f);
                        const float d2 = fmaxf(fmaf(w1h[2][3], ha[st][3], d2a + d2b), 0.0f);
                        const float d3 = fmaxf(fmaf(w1h[3][3], ha[st][3], d3a + d3b), 0.0f);
                        const float d4 = fmaxf(fmaf(w1h[4][3], ha[st][3], d4a + d4b), 0.0f);
                        const float q1 = fmaf(w2v[0], d0, fmaf(w2v[1], d1, b2v));
                        const float q2 = fmaf(w2v[2], d2, fmaf(w2v[3], d3, w2v[4] * d4));
                        zst[st] += fmaxf(q1 + q2, 0.0f);

                        // keep z at t == j (cndmask, no exec churn); one LDS write per chunk
                        zk[st] = (j == t) ? zst[st] : zk[st];
                    }
                }
            }
            // chunk-end z stores: each lane writes its kept t = ch*8 + j
            zls[bl * ZSTR + ch * TC + j]        = zk[0];
            zls[(8 + bl) * ZSTR + ch * TC + j]  = zk[1];
        }
        __syncthreads();   // P(ch+1) ready; buf[ch&1] free for producer
    }

    // coalesced output store, both waves (zls visible via final barrier)
#pragma unroll
    for (int it = 0; it < 7; ++it) {
        const int idx = tid + it * 128;          // float4 index, NB*50 = 800 total
        if (idx < NB * (T_LEN / 4)) {
            const int bb = idx / 50, rem = idx - bb * 50;
            *(float4*)&out[(size_t)(bg + bb) * T_LEN + rem * 4] =
                *(const float4*)&zls[bb * ZSTR + rem * 4];
        }
    }
}

extern "C" void kernel_launch(void* const* d_in, const int* in_sizes, int n_in,
                              void* d_out, int out_size, void* d_ws, size_t ws_size,
                              hipStream_t stream) {
    const float* x    = (const float*)d_in[0];
    const float* z0   = (const float*)d_in[1];
    const float* W_ih = (const float*)d_in[2];
    const float* W_hh = (const float*)d_in[3];
    const float* b_ih = (const float*)d_in[4];
    const float* b_hh = (const float*)d_in[5];
    const float* W1   = (const float*)d_in[6];
    const float* b1   = (const float*)d_in[7];
    const float* W2   = (const float*)d_in[8];
    const float* b2   = (const float*)d_in[9];
    float* out = (float*)d_out;

    const int B = in_sizes[1];
    dim3 grid(B / NB), block(128);
    hipLaunchKernelGGL(mono_lstm_kernel, grid, block, 0, stream,
                       x, z0, W_ih, W_hh, b_ih, b_hh, W1, b1, W2, b2, out);
}

// Round 4
// 194.028 us; speedup vs baseline: 1.1211x; 1.1211x over previous
//
#include <hip/hip_runtime.h>

#define T_LEN 200
#define F_IN  32
#define TC    8                 // timesteps per chunk; 200 = 25 * 8
#define NCH   (T_LEN / TC)
#define NB    8                 // batches per block
#define PSTR  264               // P stride per batch (dwords): 8t*32 + 8 pad -> 2-way banks (free)
#define ZSTR  204               // z stride per batch (dwords), 16B-aligned rows

#define QP(a,b,c,d) ((a)|((b)<<2)|((c)<<4)|((d)<<6))
#define DPP_HM 0x141            // row_half_mirror: lane^7 within each 8-group

typedef short  bf16x8  __attribute__((ext_vector_type(8)));
typedef float  floatx4 __attribute__((ext_vector_type(4)));

template <int CTRL>
__device__ __forceinline__ float dppf(float v) {
    return __int_as_float(__builtin_amdgcn_update_dpp(
        0, __float_as_int(v), CTRL, 0xF, 0xF, true));
}
// truncation bf16 split: x ~= hi + lo, |err| ~ 2^-16 rel
__device__ __forceinline__ void bfsplit(float x, short& hi, short& lo) {
    unsigned u = __float_as_uint(x);
    unsigned short h = (unsigned short)(u >> 16);
    float fh = __uint_as_float(((unsigned)h) << 16);
    float r  = x - fh;
    hi = (short)h;
    lo = (short)(__float_as_uint(r) >> 16);
}

// next-chunk P prefetch: 32 ds_reads issued at chunk top, consumed next chunk
#define LOADPV(PL, LB)                                                      \
    do {                                                                    \
        _Pragma("unroll")                                                   \
        for (int _t = 0; _t < TC; ++_t) {                                   \
            const int _a = (LB) + _t * 32 + j;                              \
            PL[0][_t] = pls[_a];      PL[1][_t] = pls[_a + 8];              \
            PL[2][_t] = pls[_a + 16]; PL[3][_t] = pls[_a + 24];             \
        }                                                                   \
    } while (0)

// balanced head unit: three parallel chains (depth 3,3,2) + 2 adds + relu
#define HUNIT(m)                                                            \
    fmaxf((fmaf(w1h[m][2], ha2, fmaf(w1h[m][1], ha1, fmaf(w1h[m][0], ha0, b1v[m]))) \
         + fmaf(w1h[m][5], ha5, fmaf(w1h[m][4], ha4, w1h[m][3] * ha3)))     \
         + fmaf(w1h[m][7], ha7, w1h[m][6] * ha6), 0.0f)

#define STEP8(PU)                                                           \
    do {                                                                    \
        _Pragma("unroll")                                                   \
        for (int t = 0; t < TC; ++t) {                                      \
            float mi = fmaf(whi[0], ha0, fmaf(whi[1], ha1,                  \
                       fmaf(whi[2], ha2, fmaf(whi[3], ha3, PU[0][t]))));    \
            float ni = fmaf(whi[4], ha4, fmaf(whi[5], ha5,                  \
                       fmaf(whi[6], ha6, whi[7] * ha7)));                   \
            float mf = fmaf(whf[0], ha0, fmaf(whf[1], ha1,                  \
                       fmaf(whf[2], ha2, fmaf(whf[3], ha3, PU[1][t]))));    \
            float nf = fmaf(whf[4], ha4, fmaf(whf[5], ha5,                  \
                       fmaf(whf[6], ha6, whf[7] * ha7)));                   \
            float mg = fmaf(whg[0], ha0, fmaf(whg[1], ha1,                  \
                       fmaf(whg[2], ha2, fmaf(whg[3], ha3, PU[2][t]))));    \
            float ng = fmaf(whg[4], ha4, fmaf(whg[5], ha5,                  \
                       fmaf(whg[6], ha6, whg[7] * ha7)));                   \
            float mo = fmaf(who[0], ha0, fmaf(who[1], ha1,                  \
                       fmaf(who[2], ha2, fmaf(who[3], ha3, PU[3][t]))));    \
            float no = fmaf(who[4], ha4, fmaf(who[5], ha5,                  \
                       fmaf(who[6], ha6, who[7] * ha7)));                   \
            const float ai = fmaf(wzi, z, mi + ni);                         \
            const float af = fmaf(wzf, z, mf + nf);                         \
            const float ag = fmaf(wzg, z, mg + ng);                         \
            const float ao = fmaf(wzo, z, mo + no);                         \
            const float si = __builtin_amdgcn_rcpf(1.0f + __builtin_amdgcn_exp2f(ai)); \
            const float sf = __builtin_amdgcn_rcpf(1.0f + __builtin_amdgcn_exp2f(af)); \
            const float sg = __builtin_amdgcn_rcpf(1.0f + __builtin_amdgcn_exp2f(ag)); \
            const float so = __builtin_amdgcn_rcpf(1.0f + __builtin_amdgcn_exp2f(ao)); \
            /* scaled-cell domain: ck = c*(-2log2e); prodk = si*tanh(g)*(-2log2e) */ \
            const float si2K  = si * C2K;                                   \
            const float msiK  = si * CPK;                                   \
            const float prodk = fmaf(si2K, sg, msiK);                       \
            ck = fmaf(sf, ck, prodk);                                       \
            const float ec  = __builtin_amdgcn_exp2f(ck);                   \
            const float rc  = __builtin_amdgcn_rcpf(1.0f + ec);             \
            const float so2 = so + so;                                      \
            const float hn  = fmaf(so2, rc, -so);      /* so*tanh(c) */     \
            ha0 = hn;                                                       \
            ha1 = dppf<QP(1, 0, 3, 2)>(hn);                                 \
            ha2 = dppf<QP(2, 3, 0, 1)>(hn);                                 \
            ha3 = dppf<QP(3, 2, 1, 0)>(hn);                                 \
            const float t7 = dppf<DPP_HM>(hn);                              \
            ha7 = t7;                                                       \
            ha4 = dppf<QP(3, 2, 1, 0)>(t7);                                 \
            ha5 = dppf<QP(2, 3, 0, 1)>(t7);                                 \
            ha6 = dppf<QP(1, 0, 3, 2)>(t7);                                 \
            const float d0 = HUNIT(0);                                      \
            const float d1 = HUNIT(1);                                      \
            const float d2 = HUNIT(2);                                      \
            const float d3 = HUNIT(3);                                      \
            const float d4 = HUNIT(4);                                      \
            const float q1 = fmaf(w2v[1], d1, fmaf(w2v[0], d0, b2v));       \
            const float q2 = fmaf(w2v[2], d2, fmaf(w2v[3], d3, w2v[4] * d4)); \
            z += fmaxf(q1 + q2, 0.0f);                                      \
            zk = (j == t) ? z : zk;                                         \
        }                                                                   \
    } while (0)

__launch_bounds__(128, 1)
__global__ void mono_lstm_kernel(const float* __restrict__ x,
                                 const float* __restrict__ z0,
                                 const float* __restrict__ W_ih,
                                 const float* __restrict__ W_hh,
                                 const float* __restrict__ b_ih,
                                 const float* __restrict__ b_hh,
                                 const float* __restrict__ W1,
                                 const float* __restrict__ b1,
                                 const float* __restrict__ W2,
                                 const float* __restrict__ b2,
                                 float* __restrict__ out) {
    __shared__ float pls[3 * NB * PSTR];   // P triple buffer (25.3 KB)
    __shared__ float zls[NB * ZSTR];       // z output buffer (6.5 KB)

    const int tid  = threadIdx.x;         // 0..127: wave0 = consumer, wave1 = producer
    const int lane = tid & 63;
    const int wv   = tid >> 6;
    const int bl   = lane >> 3;           // local batch 0..7
    const int j    = lane & 7;            // hidden unit owned by this lane
    const int bg   = blockIdx.x * NB;

    const float L2E = 1.4426950408889634f;
    const float NSC = -L2E;               // i,f,o scale (negated for exp2(-u))
    const float NSG = -2.0f * L2E;        // g scale (tanh u = 2*sig(2u)-1)
    const float C2K = -4.0f * L2E;        // si scale for prodk (2*K, K=-2log2e)
    const float CPK =  2.0f * L2E;        // si scale for prodk (-K)

    // ================= producer (wave 1) state =================
    const int n  = lane & 15;             // MFMA N index
    const int kq = lane >> 4;
    bf16x8 Bh0, Bl0, Bh1, Bl1;
    float bias0 = 0.f, bias1 = 0.f;

    // A-fragment addressing: m = lane&15 -> (batch m>>1, t-parity m&1); k = kq*8..
    const int   am  = lane & 15;
    const float* xa = x + ((size_t)(bg + (am >> 1)) * T_LEN + (am & 1)) * F_IN + kq * 8;

    float4 rgv[8];
    auto load_x = [&](int ch) {   // x for chunk ch -> registers
#pragma unroll
        for (int s = 0; s < 4; ++s) {
            const float* p = xa + (size_t)(ch * TC + 2 * s) * F_IN;
            rgv[2 * s]     = *(const float4*)p;
            rgv[2 * s + 1] = *(const float4*)(p + 4);
        }
    };
    auto mfma_phase = [&](int buf) {  // P(chunk) from rgv -> pls[buf]
#pragma unroll
        for (int s = 0; s < 4; ++s) {
            const float xv[8] = {rgv[2*s].x, rgv[2*s].y, rgv[2*s].z, rgv[2*s].w,
                                 rgv[2*s+1].x, rgv[2*s+1].y, rgv[2*s+1].z, rgv[2*s+1].w};
            bf16x8 Ah, Al;
#pragma unroll
            for (int i = 0; i < 8; ++i) {
                short h, l;
                bfsplit(xv[i], h, l);
                Ah[i] = h; Al[i] = l;
            }
            floatx4 a0 = {bias0, bias0, bias0, bias0};
            floatx4 a1 = {bias1, bias1, bias1, bias1};
            a0 = __builtin_amdgcn_mfma_f32_16x16x32_bf16(Ah, Bh0, a0, 0, 0, 0);
            a0 = __builtin_amdgcn_mfma_f32_16x16x32_bf16(Al, Bh0, a0, 0, 0, 0);
            a0 = __builtin_amdgcn_mfma_f32_16x16x32_bf16(Ah, Bl0, a0, 0, 0, 0);
            a1 = __builtin_amdgcn_mfma_f32_16x16x32_bf16(Ah, Bh1, a1, 0, 0, 0);
            a1 = __builtin_amdgcn_mfma_f32_16x16x32_bf16(Al, Bh1, a1, 0, 0, 0);
            a1 = __builtin_amdgcn_mfma_f32_16x16x32_bf16(Ah, Bl1, a1, 0, 0, 0);
#pragma unroll
            for (int reg = 0; reg < 4; ++reg) {
                const int mr = (lane >> 4) * 4 + reg;      // C/D row = A m-row
                const int bb = mr >> 1, tt = 2 * s + (mr & 1);
                pls[buf * NB * PSTR + bb * PSTR + tt * 32 + n]      = a0[reg];
                pls[buf * NB * PSTR + bb * PSTR + tt * 32 + 16 + n] = a1[reg];
            }
        }
    };

    // ================= consumer (wave 0) state =================
    float whi[8], whf[8], whg[8], who[8];
    float wzi = 0.f, wzf = 0.f, wzg = 0.f, wzo = 0.f;
    float w1h[5][8], b1v[5], w2v[5];
    float b2v = 0.f;
    float ha0 = 0.f, ha1 = 0.f, ha2 = 0.f, ha3 = 0.f,
          ha4 = 0.f, ha5 = 0.f, ha6 = 0.f, ha7 = 0.f;   // h_{j^k}
    float ck = 0.0f;                      // scaled cell: c * (-2log2e)
    float z  = 0.f;
    float zk = 0.f;                       // z kept at t == j (per chunk)
    float pvA[4][8], pvB[4][8];           // P fragments, ping-pong across chunks

    if (wv == 1) {
        // ---- MFMA B fragments: N-tile0 rows 0..15 (i,f), tile1 rows 16..31 (g,o)
        const int row0 = n, row1 = 16 + n;
        const float sc0 = NSC;                       // rows 0..15 all i/f
        const float sc1 = (n < 8) ? NSG : NSC;       // g rows then o rows
#pragma unroll
        for (int i = 0; i < 8; ++i) {
            const int k = kq * 8 + i;
            short h, l;
            bfsplit(W_ih[row0 * 33 + k] * sc0, h, l); Bh0[i] = h; Bl0[i] = l;
            bfsplit(W_ih[row1 * 33 + k] * sc1, h, l); Bh1[i] = h; Bl1[i] = l;
        }
        bias0 = (b_ih[row0] + b_hh[row0]) * sc0;
        bias1 = (b_ih[row1] + b_hh[row1]) * sc1;

        // ---- prologue: P(0)->buf0, P(1)->buf1, x(2) in registers
        load_x(0);
        mfma_phase(0);
        load_x(1);
        mfma_phase(1);
        load_x(2);
    } else {
        // ---- recurrence weights (per lane, xor-gather order) ----
        const int ri = j, rf = 8 + j, rg_ = 16 + j, ro = 24 + j;
#pragma unroll
        for (int k = 0; k < 8; ++k) {
            whi[k] = W_hh[ri * 8 + (j ^ k)] * NSC;
            whf[k] = W_hh[rf * 8 + (j ^ k)] * NSC;
            whg[k] = W_hh[rg_ * 8 + (j ^ k)] * NSG;
            who[k] = W_hh[ro * 8 + (j ^ k)] * NSC;
        }
        wzi = W_ih[ri * 33 + 32] * NSC;
        wzf = W_ih[rf * 33 + 32] * NSC;
        wzg = W_ih[rg_ * 33 + 32] * NSG;
        wzo = W_ih[ro * 33 + 32] * NSC;

        // ---- head weights: full head per lane (xor-permuted cols) ----
#pragma unroll
        for (int m = 0; m < 5; ++m) {
#pragma unroll
            for (int k = 0; k < 8; ++k) w1h[m][k] = W1[m * 8 + (j ^ k)];
            b1v[m] = b1[m];
            w2v[m] = W2[m];
        }
        b2v = b2[0];
        z = z0[bg + bl];
    }

    __syncthreads();   // P(0), P(1) ready

    // consumer: prime pvA with P(0) (one-time LDS-latency stall)
    if (wv == 0) {
        const int lb0 = bl * PSTR;
        LOADPV(pvA, lb0);
    }

    int rb0 = 0, rb1 = 1, rb2 = 2;   // buf of P(ch), P(ch+1), P(ch+2)
    for (int ch = 0; ch < NCH; ++ch) {
        if (wv == 1) {
            // producer: stays 2 chunks ahead
            if (ch + 2 < NCH) {
                mfma_phase(rb2);
                if (ch + 3 < NCH) load_x(ch + 3);
            }
        } else {
            // prefetch next chunk's P into the other register set (off-chain,
            // hides LDS latency under this chunk's 8 steps)
            if (ch + 1 < NCH) {
                const int lb = rb1 * NB * PSTR + bl * PSTR;
                if (ch & 1) { LOADPV(pvA, lb); } else { LOADPV(pvB, lb); }
            }
            if (ch & 1) { STEP8(pvB); } else { STEP8(pvA); }
            zls[bl * ZSTR + ch * TC + j] = zk;
        }
        __syncthreads();   // P(ch+2) ready; buf rb0 free for producer
        const int rr = rb0; rb0 = rb1; rb1 = rb2; rb2 = rr;
    }

    // coalesced output store, both waves (zls visible via loop's final barrier)
#pragma unroll
    for (int it = 0; it < 4; ++it) {
        const int idx = tid + it * 128;          // float4 index, NB*50 = 400 total
        if (idx < NB * (T_LEN / 4)) {
            const int bb = idx / 50, rem = idx - bb * 50;
            *(float4*)&out[(size_t)(bg + bb) * T_LEN + rem * 4] =
                *(const float4*)&zls[bb * ZSTR + rem * 4];
        }
    }
}

extern "C" void kernel_launch(void* const* d_in, const int* in_sizes, int n_in,
                              void* d_out, int out_size, void* d_ws, size_t ws_size,
                              hipStream_t stream) {
    const float* x    = (const float*)d_in[0];
    const float* z0   = (const float*)d_in[1];
    const float* W_ih = (const float*)d_in[2];
    const float* W_hh = (const float*)d_in[3];
    const float* b_ih = (const float*)d_in[4];
    const float* b_hh = (const float*)d_in[5];
    const float* W1   = (const float*)d_in[6];
    const float* b1   = (const float*)d_in[7];
    const float* W2   = (const float*)d_in[8];
    const float* b2   = (const float*)d_in[9];
    float* out = (float*)d_out;

    const int B = in_sizes[1];
    dim3 grid(B / NB), block(128);
    hipLaunchKernelGGL(mono_lstm_kernel, grid, block, 0, stream,
                       x, z0, W_ih, W_hh, b_ih, b_hh, W1, b1, W2, b2, out);
}

// Round 5
// 177.206 us; speedup vs baseline: 1.2275x; 1.0949x over previous
//
#include <hip/hip_runtime.h>

#define T_LEN 200
#define F_IN  32
#define TC    8                 // timesteps per chunk; 200 = 25 * 8
#define NCH   (T_LEN / TC)
#define NB    8                 // batches per block
#define PSTR  264               // P stride per batch (dwords): 8t*32 + 8 pad -> 2-way banks (free)
#define ZSTR  204               // z stride per batch (dwords), 16B-aligned rows

#define QP(a,b,c,d) ((a)|((b)<<2)|((c)<<4)|((d)<<6))
#define DPP_HM 0x141            // row_half_mirror: lane^7 within each 8-group

typedef short  bf16x8  __attribute__((ext_vector_type(8)));
typedef float  floatx4 __attribute__((ext_vector_type(4)));

template <int CTRL>
__device__ __forceinline__ float dppf(float v) {
    return __int_as_float(__builtin_amdgcn_update_dpp(
        0, __float_as_int(v), CTRL, 0xF, 0xF, true));
}
// truncation bf16 split: x ~= hi + lo, |err| ~ 2^-16 rel
__device__ __forceinline__ void bfsplit(float x, short& hi, short& lo) {
    unsigned u = __float_as_uint(x);
    unsigned short h = (unsigned short)(u >> 16);
    float fh = __uint_as_float(((unsigned)h) << 16);
    float r  = x - fh;
    hi = (short)h;
    lo = (short)(__float_as_uint(r) >> 16);
}

__launch_bounds__(128, 1)
__global__ void mono_lstm_kernel(const float* __restrict__ x,
                                 const float* __restrict__ z0,
                                 const float* __restrict__ W_ih,
                                 const float* __restrict__ W_hh,
                                 const float* __restrict__ b_ih,
                                 const float* __restrict__ b_hh,
                                 const float* __restrict__ W1,
                                 const float* __restrict__ b1,
                                 const float* __restrict__ W2,
                                 const float* __restrict__ b2,
                                 float* __restrict__ out) {
    __shared__ float pls[2 * NB * PSTR];   // P double buffer
    __shared__ float zls[NB * ZSTR];       // z output buffer

    const int tid  = threadIdx.x;         // 0..127: wave0 = consumer, wave1 = producer
    const int lane = tid & 63;
    const int wv   = tid >> 6;
    const int bl   = lane >> 3;           // local batch 0..7
    const int j    = lane & 7;            // hidden unit owned by this lane
    const int bg   = blockIdx.x * NB;

    const float L2E = 1.4426950408889634f;
    const float NSC = -L2E;               // i,f,o scale (negated for exp2(-u))
    const float NSG = -2.0f * L2E;        // g scale (tanh u = 2*sig(2u)-1)

    // ================= producer (wave 1) state =================
    const int n  = lane & 15;             // MFMA N index
    const int kq = lane >> 4;
    bf16x8 Bh0, Bl0, Bh1, Bl1;
    float bias0 = 0.f, bias1 = 0.f;

    // A-fragment addressing: m = lane&15 -> (batch m>>1, t-parity m&1); k = kq*8..
    const int   am  = lane & 15;
    const float* xa = x + ((size_t)(bg + (am >> 1)) * T_LEN + (am & 1)) * F_IN + kq * 8;

    float4 rgv[8];
    auto load_x = [&](int ch) {   // x for chunk ch -> registers
#pragma unroll
        for (int s = 0; s < 4; ++s) {
            const float* p = xa + (size_t)(ch * TC + 2 * s) * F_IN;
            rgv[2 * s]     = *(const float4*)p;
            rgv[2 * s + 1] = *(const float4*)(p + 4);
        }
    };
    auto mfma_phase = [&](int buf) {  // P(chunk) from rgv -> pls[buf]
#pragma unroll
        for (int s = 0; s < 4; ++s) {
            const float xv[8] = {rgv[2*s].x, rgv[2*s].y, rgv[2*s].z, rgv[2*s].w,
                                 rgv[2*s+1].x, rgv[2*s+1].y, rgv[2*s+1].z, rgv[2*s+1].w};
            bf16x8 Ah, Al;
#pragma unroll
            for (int i = 0; i < 8; ++i) {
                short h, l;
                bfsplit(xv[i], h, l);
                Ah[i] = h; Al[i] = l;
            }
            floatx4 a0 = {bias0, bias0, bias0, bias0};
            floatx4 a1 = {bias1, bias1, bias1, bias1};
            a0 = __builtin_amdgcn_mfma_f32_16x16x32_bf16(Ah, Bh0, a0, 0, 0, 0);
            a0 = __builtin_amdgcn_mfma_f32_16x16x32_bf16(Al, Bh0, a0, 0, 0, 0);
            a0 = __builtin_amdgcn_mfma_f32_16x16x32_bf16(Ah, Bl0, a0, 0, 0, 0);
            a1 = __builtin_amdgcn_mfma_f32_16x16x32_bf16(Ah, Bh1, a1, 0, 0, 0);
            a1 = __builtin_amdgcn_mfma_f32_16x16x32_bf16(Al, Bh1, a1, 0, 0, 0);
            a1 = __builtin_amdgcn_mfma_f32_16x16x32_bf16(Ah, Bl1, a1, 0, 0, 0);
#pragma unroll
            for (int reg = 0; reg < 4; ++reg) {
                const int mr = (lane >> 4) * 4 + reg;      // C/D row = A m-row
                const int bb = mr >> 1, tt = 2 * s + (mr & 1);
                pls[buf * NB * PSTR + bb * PSTR + tt * 32 + n]      = a0[reg];
                pls[buf * NB * PSTR + bb * PSTR + tt * 32 + 16 + n] = a1[reg];
            }
        }
    };

    // ================= consumer (wave 0) state =================
    float whi[8], whf[8], whg[8], who[8];
    float wzi = 0.f, wzf = 0.f, wzg = 0.f, wzo = 0.f;
    float w1own[8];                       // W1 row j (xor-permuted), 0 for j>=5
    float b1own = 0.f, w2own = 0.f, b2v = 0.f;
    float ha0 = 0.f, ha1 = 0.f, ha2 = 0.f, ha3 = 0.f,
          ha4 = 0.f, ha5 = 0.f, ha6 = 0.f, ha7 = 0.f;   // h_{j^k}
    float c = 0.0f;
    float z = 0.f;
    float zk = 0.f;                       // z kept at t == j (per chunk)
#pragma unroll
    for (int k = 0; k < 8; ++k) w1own[k] = 0.f;

    if (wv == 1) {
        // ---- MFMA B fragments: N-tile0 rows 0..15 (i,f), tile1 rows 16..31 (g,o)
        const int row0 = n, row1 = 16 + n;
        const float sc0 = NSC;                       // rows 0..15 all i/f
        const float sc1 = (n < 8) ? NSG : NSC;       // g rows then o rows
#pragma unroll
        for (int i = 0; i < 8; ++i) {
            const int k = kq * 8 + i;
            short h, l;
            bfsplit(W_ih[row0 * 33 + k] * sc0, h, l); Bh0[i] = h; Bl0[i] = l;
            bfsplit(W_ih[row1 * 33 + k] * sc1, h, l); Bh1[i] = h; Bl1[i] = l;
        }
        bias0 = (b_ih[row0] + b_hh[row0]) * sc0;
        bias1 = (b_ih[row1] + b_hh[row1]) * sc1;

        // ---- prologue: P(0) into buf0, x(1) into registers
        load_x(0);
        mfma_phase(0);
        load_x(1);
    } else {
        // ---- recurrence weights (per lane, xor-gather order) ----
        const int ri = j, rf = 8 + j, rg_ = 16 + j, ro = 24 + j;
#pragma unroll
        for (int k = 0; k < 8; ++k) {
            whi[k] = W_hh[ri * 8 + (j ^ k)] * NSC;
            whf[k] = W_hh[rf * 8 + (j ^ k)] * NSC;
            whg[k] = W_hh[rg_ * 8 + (j ^ k)] * NSG;
            who[k] = W_hh[ro * 8 + (j ^ k)] * NSC;
        }
        wzi = W_ih[ri * 33 + 32] * NSC;
        wzf = W_ih[rf * 33 + 32] * NSC;
        wzg = W_ih[rg_ * 33 + 32] * NSG;
        wzo = W_ih[ro * 33 + 32] * NSC;

        // ---- head: DISTRIBUTED — lane j owns head unit j (j<5), others zero.
        // d_j needs h[m] = ha_{j^m} on this lane -> w1own[k] = W1[j][j^k].
        if (j < 5) {
#pragma unroll
            for (int k = 0; k < 8; ++k) w1own[k] = W1[j * 8 + (j ^ k)];
            b1own = b1[j];
            w2own = W2[j];
        }
        b2v = b2[0];
        z = z0[bg + bl];
    }

    __syncthreads();   // P(0) ready

    for (int ch = 0; ch < NCH; ++ch) {
        if (wv == 1) {
            // producer: P(ch+1) into the other buffer while consumer eats P(ch)
            if (ch + 1 < NCH) {
                mfma_phase((ch + 1) & 1);
                if (ch + 2 < NCH) load_x(ch + 2);
            }
        } else {
            // consumer: prefetch this chunk's P into registers (off-chain)
            const int base = (ch & 1) * NB * PSTR + bl * PSTR;
            float pvi[TC], pvf[TC], pvg[TC], pvo[TC];
#pragma unroll
            for (int t = 0; t < TC; ++t) {
                pvi[t] = pls[base + t * 32 + j];
                pvf[t] = pls[base + t * 32 + 8 + j];
                pvg[t] = pls[base + t * 32 + 16 + j];
                pvo[t] = pls[base + t * 32 + 24 + j];
            }

#pragma unroll
            for (int t = 0; t < TC; ++t) {
                // matvec (off z-path: starts from ha*), then +wz*z last
                float mi = fmaf(whi[0], ha0, fmaf(whi[1], ha1,
                           fmaf(whi[2], ha2, fmaf(whi[3], ha3, pvi[t]))));
                float ni = fmaf(whi[4], ha4, fmaf(whi[5], ha5,
                           fmaf(whi[6], ha6, whi[7] * ha7)));
                float mf = fmaf(whf[0], ha0, fmaf(whf[1], ha1,
                           fmaf(whf[2], ha2, fmaf(whf[3], ha3, pvf[t]))));
                float nf = fmaf(whf[4], ha4, fmaf(whf[5], ha5,
                           fmaf(whf[6], ha6, whf[7] * ha7)));
                float mg = fmaf(whg[0], ha0, fmaf(whg[1], ha1,
                           fmaf(whg[2], ha2, fmaf(whg[3], ha3, pvg[t]))));
                float ng = fmaf(whg[4], ha4, fmaf(whg[5], ha5,
                           fmaf(whg[6], ha6, whg[7] * ha7)));
                float mo = fmaf(who[0], ha0, fmaf(who[1], ha1,
                           fmaf(who[2], ha2, fmaf(who[3], ha3, pvo[t]))));
                float no = fmaf(who[4], ha4, fmaf(who[5], ha5,
                           fmaf(who[6], ha6, who[7] * ha7)));

                const float ai = fmaf(wzi, z, mi + ni);
                const float af = fmaf(wzf, z, mf + nf);
                const float ag = fmaf(wzg, z, mg + ng);
                const float ao = fmaf(wzo, z, mo + no);

                // activations: acc pre-scaled by -log2e (or -2log2e for g)
                const float si = __builtin_amdgcn_rcpf(1.0f + __builtin_amdgcn_exp2f(ai));
                const float sf = __builtin_amdgcn_rcpf(1.0f + __builtin_amdgcn_exp2f(af));
                const float sg = __builtin_amdgcn_rcpf(1.0f + __builtin_amdgcn_exp2f(ag));
                const float so = __builtin_amdgcn_rcpf(1.0f + __builtin_amdgcn_exp2f(ao));
                const float tg = fmaf(2.0f, sg, -1.0f);      // tanh(g)

                c = fmaf(sf, c, si * tg);
                const float ec = __builtin_amdgcn_exp2f(c * (-2.0f * L2E));
                const float tc = fmaf(2.0f, __builtin_amdgcn_rcpf(1.0f + ec), -1.0f);
                const float hn = so * tc;                    // h_j

                // gather h_{j^k}: pure DPP within the 8-lane group, depth 2
                ha0 = hn;
                ha1 = dppf<QP(1, 0, 3, 2)>(hn);
                ha2 = dppf<QP(2, 3, 0, 1)>(hn);
                ha3 = dppf<QP(3, 2, 1, 0)>(hn);
                const float t7 = dppf<DPP_HM>(hn);
                ha7 = t7;
                ha4 = dppf<QP(3, 2, 1, 0)>(t7);
                ha5 = dppf<QP(2, 3, 0, 1)>(t7);
                ha6 = dppf<QP(1, 0, 3, 2)>(t7);

                // head: distributed across the 8-lane group (lane j = unit j)
                float da = fmaf(w1own[2], ha2, fmaf(w1own[1], ha1,
                           fmaf(w1own[0], ha0, b1own)));
                float db = fmaf(w1own[5], ha5, fmaf(w1own[4], ha4, w1own[3] * ha3));
                float dc = fmaf(w1own[7], ha7, w1own[6] * ha6);
                const float d = fmaxf((da + db) + dc, 0.0f);
                const float e = w2own * d;                 // 0 for j>=5

                // butterfly sum over the 8-lane group (xor basis {1,2,7}):
                // every lane ends with q = sum_m e_m
                float q = e;
                q += dppf<QP(1, 0, 3, 2)>(q);
                q += dppf<QP(2, 3, 0, 1)>(q);
                q += dppf<DPP_HM>(q);

                z += fmaxf(q + b2v, 0.0f);
                zk = (j == t) ? z : zk;   // cndmask keep, no exec churn
            }
            // chunk-end z store: lane j writes its kept t = ch*8 + j
            zls[bl * ZSTR + ch * TC + j] = zk;
        }
        __syncthreads();   // P(ch+1) ready; buf[ch&1] free for producer
    }

    // coalesced output store, both waves (zls visible via loop's final barrier)
#pragma unroll
    for (int it = 0; it < 4; ++it) {
        const int idx = tid + it * 128;          // float4 index, NB*50 = 400 total
        if (idx < NB * (T_LEN / 4)) {
            const int bb = idx / 50, rem = idx - bb * 50;
            *(float4*)&out[(size_t)(bg + bb) * T_LEN + rem * 4] =
                *(const float4*)&zls[bb * ZSTR + rem * 4];
        }
    }
}

extern "C" void kernel_launch(void* const* d_in, const int* in_sizes, int n_in,
                              void* d_out, int out_size, void* d_ws, size_t ws_size,
                              hipStream_t stream) {
    const float* x    = (const float*)d_in[0];
    const float* z0   = (const float*)d_in[1];
    const float* W_ih = (const float*)d_in[2];
    const float* W_hh = (const float*)d_in[3];
    const float* b_ih = (const float*)d_in[4];
    const float* b_hh = (const float*)d_in[5];
    const float* W1   = (const float*)d_in[6];
    const float* b1   = (const float*)d_in[7];
    const float* W2   = (const float*)d_in[8];
    const float* b2   = (const float*)d_in[9];
    float* out = (float*)d_out;

    const int B = in_sizes[1];
    dim3 grid(B / NB), block(128);
    hipLaunchKernelGGL(mono_lstm_kernel, grid, block, 0, stream,
                       x, z0, W_ih, W_hh, b_ih, b_hh, W1, b1, W2, b2, out);
}